// Round 13
// baseline (162.318 us; speedup 1.0000x reference)
//
#include <hip/hip_runtime.h>
#include <math.h>

#define P 7
#define SCALE 0.125f
#define BB 4
#define CC 256
#define HH 128
#define WW 128
#define KK 512
#define NBIN 49
#define NXCD 8
#define RPX  (KK / NXCD)  // 64 ROIs per XCD slice

#define TRANS_BLOCKS 4096   // (HH*WW/64) * (CC/64) * BB
#define MASK_BLOCKS  4096   // KK*HH rows / 16 waves per block

__device__ __forceinline__ unsigned short f32_to_bf16_rne(float f) {
    unsigned int u = __float_as_uint(f);
    u += 0x7FFFu + ((u >> 16) & 1u);
    return (unsigned short)(u >> 16);
}

// Order-preserving bf16 -> u16 key. key 0 reserved = "empty/masked".
__device__ __forceinline__ unsigned short bf16_key(unsigned short b) {
    return (b & 0x8000u) ? (unsigned short)(~b) : (unsigned short)(b | 0x8000u);
}

__device__ __forceinline__ unsigned int pkmax_u16(unsigned int a, unsigned int b) {
    unsigned int d;
    asm("v_pk_max_u16 %0, %1, %2" : "=v"(d) : "v"(a), "v"(b));
    return d;
}

// ---- Fused prep: transpose+convert, mask->bitmask; block 0 also sorts ----
__global__ __launch_bounds__(1024) void prep_fused(
    const float* __restrict__ in, const float* __restrict__ masks,
    const float* __restrict__ rois,
    unsigned short* __restrict__ out, unsigned long long* __restrict__ mbits,
    int* __restrict__ perm)
{
    __shared__ float tile[64][65];    // tile[channel][pixel]
    __shared__ int skey[KK];          // used by block 0 only (sort)
    const int bid = blockIdx.x;
    const int tid = threadIdx.x;

    if (bid < TRANS_BLOCKS) {
        const int p0 = (bid & 255) * 64;        // pixel tile
        const int c0 = ((bid >> 8) & 3) * 64;   // channel tile
        const int b  = bid >> 10;               // batch
        const int tx = tid & 63;
        const int ty = tid >> 6;                // 0..15

        const float* src = in + (size_t)b * CC * (HH * WW);
#pragma unroll
        for (int j = 0; j < 64; j += 16)
            tile[ty + j][tx] =
                __builtin_nontemporal_load(&src[(size_t)(c0 + ty + j) * (HH * WW) + p0 + tx]);
        __syncthreads();

        unsigned int* dst = (unsigned int*)(out + (size_t)b * (HH * WW) * CC);
#pragma unroll
        for (int i = 0; i < 2; ++i) {
            const int flat = i * 1024 + tid;
            const int px = flat >> 5;
            const int cp = flat & 31;
            const unsigned int lo = bf16_key(f32_to_bf16_rne(tile[cp * 2][px]));
            const unsigned int hi = bf16_key(f32_to_bf16_rne(tile[cp * 2 + 1][px]));
            dst[((size_t)(p0 + px) * CC + c0) / 2 + cp] = lo | (hi << 16);
        }

        if (bid == 0) {
            // deterministic rank sort of 512 ROIs by key=(batch,start-row);
            // block 0 runs first, so this hides under the other blocks
            __syncthreads();
            if (tid < KK) {
                const float* r = rois + (size_t)tid * 5;
                const int rb = (int)r[0];
                int rsh = (int)rintf(r[2] * SCALE);
                rsh = min(max(rsh, 0), HH - 1);
                skey[tid] = rb * HH + rsh;
            }
            __syncthreads();
            if (tid < KK) {
                const int mykey = skey[tid];
                int pos = 0;
                for (int j = 0; j < KK; ++j) {
                    const int kj = skey[j];
                    pos += (kj < mykey) || (kj == mykey && j < tid);
                }
                perm[pos] = tid;
            }
        }
    } else {
        const int mbid = bid - TRANS_BLOCKS;
        const int wv   = tid >> 6;              // 0..15
        const int lane = tid & 63;
        const int row  = mbid * 16 + wv;        // 0 .. KK*HH-1
        const float* mr = masks + (size_t)row * WW;
        const unsigned long long b0 = __ballot(mr[lane] > 0.5f);
        const unsigned long long b1 = __ballot(mr[64 + lane] > 0.5f);
        if (lane == 0) {
            mbits[(size_t)row * 2]     = b0;
            mbits[(size_t)row * 2 + 1] = b1;
        }
    }
}

// ---- Pool: one wave per (ROI, ph) row-strip, all 7 pw bins ----
__global__ __launch_bounds__(256) void pool_strip(
    const unsigned int* __restrict__ fbase,         // [B,HW,C/2] packed keys
    const float* __restrict__ rois,                 // [K,5]
    const unsigned long long* __restrict__ mbits,   // [K,H,2]
    const int* __restrict__ perm,                   // [K] sorted ROI order
    float* __restrict__ out)                        // [K,C,P,P]
{
    // pid = x + 8*(2q + s): XCD x gets sorted slice [x*64,(x+1)*64);
    // the two blocks of one ROI (s=0,1) share the same XCD.
    const int pid = blockIdx.x;                 // 0 .. KK*2-1
    const int x   = pid & (NXCD - 1);
    const int t   = pid >> 3;
    const int q   = t >> 1;                     // ROI within slice, 0..63
    const int s   = t & 1;                      // strip half
    const int k   = __builtin_amdgcn_readfirstlane(perm[x * RPX + q]);

    const int wv   = threadIdx.x >> 6;
    const int lane = threadIdx.x & 63;
    const int ph   = s * 4 + wv;                // 0..7
    if (ph >= P) return;                        // wave-uniform (ph==7 idle)

    const int half = lane >> 5;                 // even/odd pixel of each pair
    const int c4   = (lane & 31) * 4;           // uint offset: 8 channels

    const float* roi = rois + (size_t)k * 5;
    const int b  = __builtin_amdgcn_readfirstlane((int)roi[0]);
    const int sw = (int)rintf(roi[1] * SCALE);
    const int sh = (int)rintf(roi[2] * SCALE);
    const int ew = (int)rintf(roi[3] * SCALE);
    const int eh = (int)rintf(roi[4] * SCALE);
    const int roi_w = max(ew - sw + 1, 1);
    const int roi_h = max(eh - sh + 1, 1);

    const int hs = __builtin_amdgcn_readfirstlane(min(max((ph * roi_h) / P + sh, 0), HH));
    const int he = __builtin_amdgcn_readfirstlane(min(max(((ph + 1) * roi_h + P - 1) / P + sh, 0), HH));

    int wsb[P], web[P];
#pragma unroll
    for (int j = 0; j < P; ++j) {
        wsb[j] = __builtin_amdgcn_readfirstlane(min(max((j * roi_w) / P + sw, 0), WW));
        web[j] = __builtin_amdgcn_readfirstlane(min(max(((j + 1) * roi_w + P - 1) / P + sw, 0), WW));
    }

    const unsigned int* fb = fbase
        + (unsigned int)b * (unsigned int)(HH * WW * (CC / 2))
        + (unsigned int)(half * (CC / 2) + c4);
    const unsigned long long* mrow = mbits + (size_t)k * (HH * 2);

    unsigned int acc[P][4];
#pragma unroll
    for (int j = 0; j < P; ++j) {
        acc[j][0] = 0; acc[j][1] = 0; acc[j][2] = 0; acc[j][3] = 0;
    }

    const int sh0 = 0 + half, sh1 = 2 + half, sh2 = 4 + half, sh3 = 6 + half;

    for (int h = hs; h < he; ++h) {
        const unsigned long long lov = mrow[2 * h];
        const unsigned long long hiv = mrow[2 * h + 1];
        // wave-uniform mask words -> SGPRs (SALU shifts, no VALU cost)
        const unsigned int ll  = __builtin_amdgcn_readfirstlane((unsigned int)lov);
        const unsigned int lh  = __builtin_amdgcn_readfirstlane((unsigned int)(lov >> 32));
        const unsigned int hl  = __builtin_amdgcn_readfirstlane((unsigned int)hiv);
        const unsigned int hh2 = __builtin_amdgcn_readfirstlane((unsigned int)(hiv >> 32));
        const unsigned long long lo = ((unsigned long long)lh << 32) | ll;
        const unsigned long long hi = ((unsigned long long)hh2 << 32) | hl;

        const unsigned int* frow = fb + (unsigned int)h * (unsigned int)(WW * (CC / 2));

#pragma unroll
        for (int j = 0; j < P; ++j) {
            const int bl = wsb[j], br = web[j];
            for (int w0 = bl; w0 < br; w0 += 8) {
                unsigned long long v;
                if (w0 >= 64)      v = hi >> (w0 - 64);
                else if (w0 == 0)  v = lo;
                else               v = (lo >> w0) | (hi << (64 - w0));
                unsigned int chunk = (unsigned int)v & 0xFFu;
                const int n = br - w0;                   // valid pixel count
                chunk &= (n >= 8) ? 0xFFu : ((1u << n) - 1u);

                // base + imm-offset pixel pairs (1 KB apart); over-read past
                // br is masked off (memory valid: 32 MiB key buffer + mbits)
                const unsigned int* basep = frow + (unsigned int)w0 * (CC / 2);
                const uint4 k0 = *(const uint4*)(basep);
                const uint4 k1 = *(const uint4*)(basep + 256);
                const uint4 k2 = *(const uint4*)(basep + 512);
                const uint4 k3 = *(const uint4*)(basep + 768);

                const unsigned int m0 = 0u - ((chunk >> sh0) & 1u);
                const unsigned int m1 = 0u - ((chunk >> sh1) & 1u);
                const unsigned int m2 = 0u - ((chunk >> sh2) & 1u);
                const unsigned int m3 = 0u - ((chunk >> sh3) & 1u);

                acc[j][0] = pkmax_u16(acc[j][0], k0.x & m0);
                acc[j][1] = pkmax_u16(acc[j][1], k0.y & m0);
                acc[j][2] = pkmax_u16(acc[j][2], k0.z & m0);
                acc[j][3] = pkmax_u16(acc[j][3], k0.w & m0);
                acc[j][0] = pkmax_u16(acc[j][0], k1.x & m1);
                acc[j][1] = pkmax_u16(acc[j][1], k1.y & m1);
                acc[j][2] = pkmax_u16(acc[j][2], k1.z & m1);
                acc[j][3] = pkmax_u16(acc[j][3], k1.w & m1);
                acc[j][0] = pkmax_u16(acc[j][0], k2.x & m2);
                acc[j][1] = pkmax_u16(acc[j][1], k2.y & m2);
                acc[j][2] = pkmax_u16(acc[j][2], k2.z & m2);
                acc[j][3] = pkmax_u16(acc[j][3], k2.w & m2);
                acc[j][0] = pkmax_u16(acc[j][0], k3.x & m3);
                acc[j][1] = pkmax_u16(acc[j][1], k3.y & m3);
                acc[j][2] = pkmax_u16(acc[j][2], k3.z & m3);
                acc[j][3] = pkmax_u16(acc[j][3], k3.w & m3);
            }
        }
    }

    // combine pixel-halves (lane i <-> i+32 hold same channels)
#pragma unroll
    for (int j = 0; j < P; ++j) {
        acc[j][0] = pkmax_u16(acc[j][0], (unsigned int)__shfl_xor((int)acc[j][0], 32, 64));
        acc[j][1] = pkmax_u16(acc[j][1], (unsigned int)__shfl_xor((int)acc[j][1], 32, 64));
        acc[j][2] = pkmax_u16(acc[j][2], (unsigned int)__shfl_xor((int)acc[j][2], 32, 64));
        acc[j][3] = pkmax_u16(acc[j][3], (unsigned int)__shfl_xor((int)acc[j][3], 32, 64));
    }

    if (half == 0) {
        float* o = out + ((size_t)k * CC + (size_t)c4 * 2) * NBIN + ph * P;
#pragma unroll
        for (int j = 0; j < 8; ++j) {          // channel within lane
#pragma unroll
            for (int pwv = 0; pwv < P; ++pwv) {
                const unsigned int d = acc[pwv][j >> 1];
                const unsigned int key = (j & 1) ? (d >> 16) : (d & 0xFFFFu);
                float r;
                if (key == 0u) {
                    r = 0.0f;                   // empty / fully-masked bin
                } else {
                    const unsigned int bbits =
                        (key & 0x8000u) ? (key ^ 0x8000u) : (~key & 0xFFFFu);
                    r = __uint_as_float(bbits << 16);
                }
                o[(size_t)j * NBIN + pwv] = r;
            }
        }
    }
}

// ---------- Fallback (NCHW direct, correctness-only path) ----------
__global__ __launch_bounds__(256) void ROIPool_nchw_kernel(
    const float* __restrict__ inputs, const float* __restrict__ rois,
    const float* __restrict__ masks, float* __restrict__ out)
{
    const int k  = blockIdx.x;
    const int ph = blockIdx.y;
    const int c  = threadIdx.x;

    const float* roi = rois + k * 5;
    const int b  = (int)roi[0];
    const int sw = (int)rintf(roi[1] * SCALE);
    const int sh = (int)rintf(roi[2] * SCALE);
    const int ew = (int)rintf(roi[3] * SCALE);
    const int eh = (int)rintf(roi[4] * SCALE);
    const int roi_w = max(ew - sw + 1, 1);
    const int roi_h = max(eh - sh + 1, 1);

    const int hs = min(max((ph * roi_h) / P + sh, 0), HH);
    const int he = min(max(((ph + 1) * roi_h + P - 1) / P + sh, 0), HH);

    int wsb[P], web[P];
#pragma unroll
    for (int pw = 0; pw < P; ++pw) {
        wsb[pw] = min(max((pw * roi_w) / P + sw, 0), WW);
        web[pw] = min(max(((pw + 1) * roi_w + P - 1) / P + sw, 0), WW);
    }

    const float* f = inputs + ((size_t)b * CC + c) * (HH * WW);
    const float* m = masks  + (size_t)k * (HH * WW);

    float vmax[P];
#pragma unroll
    for (int pw = 0; pw < P; ++pw) vmax[pw] = -INFINITY;

    for (int h = hs; h < he; ++h) {
        const float* frow = f + h * WW;
        const float* mrow = m + h * WW;
#pragma unroll
        for (int pw = 0; pw < P; ++pw) {
            float v = vmax[pw];
            for (int w = wsb[pw]; w < web[pw]; ++w)
                if (mrow[w] > 0.5f) v = fmaxf(v, frow[w]);
            vmax[pw] = v;
        }
    }

    float* o = out + (((size_t)k * CC + c) * P + ph) * P;
#pragma unroll
    for (int pw = 0; pw < P; ++pw) {
        const float v = vmax[pw];
        o[pw] = isinf(v) ? 0.0f : v;
    }
}

extern "C" void kernel_launch(void* const* d_in, const int* in_sizes, int n_in,
                              void* d_out, int out_size, void* d_ws, size_t ws_size,
                              hipStream_t stream) {
    const float* inputs = (const float*)d_in[0];
    const float* rois   = (const float*)d_in[1];
    const float* masks  = (const float*)d_in[2];
    float* out = (float*)d_out;

    const size_t keys_bytes  = (size_t)BB * CC * HH * WW * sizeof(unsigned short); // 32 MiB
    const size_t mbits_bytes = (size_t)KK * HH * 2 * sizeof(unsigned long long);   // 1 MiB
    const size_t perm_bytes  = (size_t)KK * sizeof(int);                           // 2 KiB

    if (ws_size >= keys_bytes + mbits_bytes + perm_bytes) {
        unsigned short* fT = (unsigned short*)d_ws;
        unsigned long long* mb = (unsigned long long*)((char*)d_ws + keys_bytes);
        int* perm = (int*)((char*)d_ws + keys_bytes + mbits_bytes);
        {
            dim3 grid(TRANS_BLOCKS + MASK_BLOCKS);
            dim3 block(1024);
            prep_fused<<<grid, block, 0, stream>>>(inputs, masks, rois, fT, mb, perm);
        }
        {
            dim3 grid(KK * 2);
            dim3 block(256);
            pool_strip<<<grid, block, 0, stream>>>((const unsigned int*)fT, rois, mb, perm, out);
        }
    } else {
        dim3 grid(KK, P);
        dim3 block(CC);
        ROIPool_nchw_kernel<<<grid, block, 0, stream>>>(inputs, rois, masks, out);
    }
}

// Round 14
// 128.848 us; speedup vs baseline: 1.2598x; 1.2598x over previous
//
#include <hip/hip_runtime.h>
#include <math.h>

#define P 7
#define SCALE 0.125f
#define BB 4
#define CC 256
#define HH 128
#define WW 128
#define KK 512
#define NBIN 49
#define NXCD 8
#define RPX  (KK / NXCD)  // 64 ROIs per XCD slice

#define TRANS_BLOCKS 4096   // (HH*WW/64) * (CC/64) * BB
#define MASK_BLOCKS  4096   // KK*HH rows / 16 waves per block

__device__ __forceinline__ unsigned short f32_to_bf16_rne(float f) {
    unsigned int u = __float_as_uint(f);
    u += 0x7FFFu + ((u >> 16) & 1u);
    return (unsigned short)(u >> 16);
}

// Order-preserving bf16 -> u16 key. key 0 reserved = "empty/masked".
__device__ __forceinline__ unsigned short bf16_key(unsigned short b) {
    return (b & 0x8000u) ? (unsigned short)(~b) : (unsigned short)(b | 0x8000u);
}

__device__ __forceinline__ unsigned int pkmax_u16(unsigned int a, unsigned int b) {
    unsigned int d;
    asm("v_pk_max_u16 %0, %1, %2" : "=v"(d) : "v"(a), "v"(b));
    return d;
}

// ---- Fused prep: transpose+convert, mask->bitmask; block 0 sorts + geo ----
__global__ __launch_bounds__(1024) void prep_fused(
    const float* __restrict__ in, const float* __restrict__ masks,
    const float* __restrict__ rois,
    unsigned short* __restrict__ out, unsigned long long* __restrict__ mbits,
    unsigned int* __restrict__ kb, unsigned short* __restrict__ rowb,
    unsigned short* __restrict__ colb)
{
    __shared__ float tile[64][65];    // tile[channel][pixel]
    __shared__ int skey[KK];          // block 0 only (sort)
    const int bid = blockIdx.x;
    const int tid = threadIdx.x;

    if (bid < TRANS_BLOCKS) {
        const int p0 = (bid & 255) * 64;        // pixel tile
        const int c0 = ((bid >> 8) & 3) * 64;   // channel tile
        const int b  = bid >> 10;               // batch
        const int tx = tid & 63;
        const int ty = tid >> 6;                // 0..15

        const float* src = in + (size_t)b * CC * (HH * WW);
#pragma unroll
        for (int j = 0; j < 64; j += 16)
            tile[ty + j][tx] =
                __builtin_nontemporal_load(&src[(size_t)(c0 + ty + j) * (HH * WW) + p0 + tx]);
        __syncthreads();

        unsigned int* dst = (unsigned int*)(out + (size_t)b * (HH * WW) * CC);
#pragma unroll
        for (int i = 0; i < 2; ++i) {
            const int flat = i * 1024 + tid;
            const int px = flat >> 5;
            const int cp = flat & 31;
            const unsigned int lo = bf16_key(f32_to_bf16_rne(tile[cp * 2][px]));
            const unsigned int hi = bf16_key(f32_to_bf16_rne(tile[cp * 2 + 1][px]));
            dst[((size_t)(p0 + px) * CC + c0) / 2 + cp] = lo | (hi << 16);
        }

        if (bid == 0) {
            // sort 512 ROIs by (batch, start-row) + emit geometry records;
            // block 0 runs first so this hides under the other blocks
            __syncthreads();
            if (tid < KK) {
                const float* r = rois + (size_t)tid * 5;
                const int rb = (int)r[0];
                int rsh = (int)rintf(r[2] * SCALE);
                rsh = min(max(rsh, 0), HH - 1);
                skey[tid] = rb * HH + rsh;
            }
            __syncthreads();
            if (tid < KK) {
                const int mykey = skey[tid];
                int pos = 0;
                for (int j = 0; j < KK; ++j) {
                    const int kj = skey[j];
                    pos += (kj < mykey) || (kj == mykey && j < tid);
                }
                // geometry record at sorted position
                const float* r = rois + (size_t)tid * 5;
                const int b  = (int)r[0];
                const int sw = (int)rintf(r[1] * SCALE);
                const int sh = (int)rintf(r[2] * SCALE);
                const int ew = (int)rintf(r[3] * SCALE);
                const int eh = (int)rintf(r[4] * SCALE);
                const int roi_w = max(ew - sw + 1, 1);
                const int roi_h = max(eh - sh + 1, 1);
                kb[pos] = (unsigned int)tid | ((unsigned int)b << 16);
#pragma unroll
                for (int j = 0; j < P; ++j) {
                    const int hs = min(max((j * roi_h) / P + sh, 0), HH);
                    const int he = min(max(((j + 1) * roi_h + P - 1) / P + sh, 0), HH);
                    const int ws = min(max((j * roi_w) / P + sw, 0), WW);
                    const int we = min(max(((j + 1) * roi_w + P - 1) / P + sw, 0), WW);
                    rowb[(pos << 3) + j] = (unsigned short)(hs | (he << 8));
                    colb[(pos << 3) + j] = (unsigned short)(ws | (we << 8));
                }
                rowb[(pos << 3) + 7] = 0;
                colb[(pos << 3) + 7] = 0;   // empty slot: pair (6,7) does no j1 work
            }
        }
    } else {
        const int mbid = bid - TRANS_BLOCKS;
        const int wv   = tid >> 6;              // 0..15
        const int lane = tid & 63;
        const int row  = mbid * 16 + wv;        // 0 .. KK*HH-1
        const float* mr = masks + (size_t)row * WW;
        const unsigned long long b0 = __ballot(mr[lane] > 0.5f);
        const unsigned long long b1 = __ballot(mr[64 + lane] > 0.5f);
        if (lane == 0) {
            mbits[(size_t)row * 2]     = b0;
            mbits[(size_t)row * 2 + 1] = b1;
        }
    }
}

// ---- Pool: one wave per (ROI, ph, pw-pair); geo records; VALU mask path ----
__global__ __launch_bounds__(256) void pool_pair(
    const unsigned int* __restrict__ fbase,         // [B,HW,C/2] packed keys
    const unsigned int* __restrict__ kb,            // [K] k | b<<16 (sorted)
    const unsigned short* __restrict__ rowb,        // [K,8] hs|he<<8 (sorted)
    const unsigned short* __restrict__ colb,        // [K,8] ws|we<<8 (sorted)
    const unsigned long long* __restrict__ mbits,   // [K,H,2]
    float* __restrict__ out)                        // [K,C,P,P]
{
    // pid = x + 8*(g + 7*q): XCD x gets sorted slice [x*64,(x+1)*64);
    // the 7 blocks of one ROI are dispatch-adjacent on the same XCD.
    const int pid = blockIdx.x;                 // 0 .. KK*7-1
    const int x   = pid & (NXCD - 1);
    const int t   = pid >> 3;
    const int g   = t % 7;
    const int q   = t / 7;                      // 0..63
    const int i   = x * RPX + q;                // sorted ROI index

    const int wv   = threadIdx.x >> 6;
    const int lane = threadIdx.x & 63;
    const int u    = g * 4 + wv;                // unit 0..27
    const int ph   = u >> 2;
    const int bp   = u & 3;
    const int j0   = bp * 2;                    // pw bins j0, j0+1
    const int j1   = j0 + 1;                    // slot 7 is empty (prep wrote 0)

    const int half = lane >> 5;                 // even/odd pixel of each pair
    const int c4   = (lane & 31) * 4;           // uint offset: 8 channels

    // prologue: 4 independent small loads (all L1/L2-hot, 18 KB total)
    const unsigned int kbv = kb[i];
    const int k = kbv & 0xFFFF;
    const int b = (kbv >> 16) & 0xFF;
    const unsigned int rb  = rowb[(i << 3) + ph];
    const unsigned int cb0 = colb[(i << 3) + j0];
    const unsigned int cb1 = colb[(i << 3) + j1];
    const int hs = rb & 0xFF,  he  = (rb >> 8) & 0xFF;
    const int ws0 = cb0 & 0xFF, we0 = (cb0 >> 8) & 0xFF;
    const int ws1 = cb1 & 0xFF, we1 = (cb1 >> 8) & 0xFF;

    const unsigned int* fb = fbase
        + (unsigned int)b * (unsigned int)(HH * WW * (CC / 2))
        + (unsigned int)(half * (CC / 2) + c4);
    const unsigned long long* mrow = mbits + (size_t)k * (HH * 2);

    unsigned int p0 = 0, p1 = 0, p2 = 0, p3 = 0;   // bin j0 accumulators
    unsigned int r0 = 0, r1 = 0, r2 = 0, r3 = 0;   // bin j1 accumulators

    const int sh0 = 0 + half, sh1 = 2 + half, sh2 = 4 + half, sh3 = 6 + half;

#define DO_BIN(BL, BR, A0, A1, A2, A3) do {                                    \
        for (int w0 = (BL); w0 < (BR); w0 += 8) {                              \
            unsigned long long v;                                              \
            if (w0 >= 64)      v = hi >> (w0 - 64);                            \
            else if (w0 == 0)  v = lo;                                         \
            else               v = (lo >> w0) | (hi << (64 - w0));             \
            unsigned int chunk = (unsigned int)v & 0xFFu;                      \
            const int n = (BR) - w0;                                           \
            chunk &= (n >= 8) ? 0xFFu : ((1u << n) - 1u);                      \
            const unsigned int* basep = frow + (unsigned int)w0 * (CC / 2);    \
            const uint4 k0 = *(const uint4*)(basep);                           \
            const uint4 k1 = *(const uint4*)(basep + 256);                     \
            const uint4 k2 = *(const uint4*)(basep + 512);                     \
            const uint4 k3 = *(const uint4*)(basep + 768);                     \
            const unsigned int m0 = 0u - ((chunk >> sh0) & 1u);                \
            const unsigned int m1 = 0u - ((chunk >> sh1) & 1u);                \
            const unsigned int m2 = 0u - ((chunk >> sh2) & 1u);                \
            const unsigned int m3 = 0u - ((chunk >> sh3) & 1u);                \
            A0 = pkmax_u16(A0, k0.x & m0); A1 = pkmax_u16(A1, k0.y & m0);      \
            A2 = pkmax_u16(A2, k0.z & m0); A3 = pkmax_u16(A3, k0.w & m0);      \
            A0 = pkmax_u16(A0, k1.x & m1); A1 = pkmax_u16(A1, k1.y & m1);      \
            A2 = pkmax_u16(A2, k1.z & m1); A3 = pkmax_u16(A3, k1.w & m1);      \
            A0 = pkmax_u16(A0, k2.x & m2); A1 = pkmax_u16(A1, k2.y & m2);      \
            A2 = pkmax_u16(A2, k2.z & m2); A3 = pkmax_u16(A3, k2.w & m2);      \
            A0 = pkmax_u16(A0, k3.x & m3); A1 = pkmax_u16(A1, k3.y & m3);      \
            A2 = pkmax_u16(A2, k3.z & m3); A3 = pkmax_u16(A3, k3.w & m3);      \
        }                                                                      \
    } while (0)

#pragma unroll 2
    for (int h = hs; h < he; ++h) {
        const unsigned long long lo = mrow[2 * h];
        const unsigned long long hi = mrow[2 * h + 1];
        const unsigned int* frow = fb + (unsigned int)h * (unsigned int)(WW * (CC / 2));
        DO_BIN(ws0, we0, p0, p1, p2, p3);
        DO_BIN(ws1, we1, r0, r1, r2, r3);
    }
#undef DO_BIN

    // combine pixel-halves (lane i <-> i+32 hold same channels)
    p0 = pkmax_u16(p0, (unsigned int)__shfl_xor((int)p0, 32, 64));
    p1 = pkmax_u16(p1, (unsigned int)__shfl_xor((int)p1, 32, 64));
    p2 = pkmax_u16(p2, (unsigned int)__shfl_xor((int)p2, 32, 64));
    p3 = pkmax_u16(p3, (unsigned int)__shfl_xor((int)p3, 32, 64));
    r0 = pkmax_u16(r0, (unsigned int)__shfl_xor((int)r0, 32, 64));
    r1 = pkmax_u16(r1, (unsigned int)__shfl_xor((int)r1, 32, 64));
    r2 = pkmax_u16(r2, (unsigned int)__shfl_xor((int)r2, 32, 64));
    r3 = pkmax_u16(r3, (unsigned int)__shfl_xor((int)r3, 32, 64));

    if (half == 0) {
        const unsigned int accA[4] = {p0, p1, p2, p3};
        const unsigned int accB[4] = {r0, r1, r2, r3};
        float* o = out + ((size_t)k * CC + (size_t)c4 * 2) * NBIN + ph * P;
#pragma unroll
        for (int j = 0; j < 8; ++j) {          // channel within lane
            const unsigned int dA = accA[j >> 1];
            const unsigned int keyA = (j & 1) ? (dA >> 16) : (dA & 0xFFFFu);
            float rA;
            if (keyA == 0u) rA = 0.0f;
            else {
                const unsigned int bb =
                    (keyA & 0x8000u) ? (keyA ^ 0x8000u) : (~keyA & 0xFFFFu);
                rA = __uint_as_float(bb << 16);
            }
            o[(size_t)j * NBIN + j0] = rA;
            if (j1 < P) {
                const unsigned int dB = accB[j >> 1];
                const unsigned int keyB = (j & 1) ? (dB >> 16) : (dB & 0xFFFFu);
                float rB;
                if (keyB == 0u) rB = 0.0f;
                else {
                    const unsigned int bb =
                        (keyB & 0x8000u) ? (keyB ^ 0x8000u) : (~keyB & 0xFFFFu);
                    rB = __uint_as_float(bb << 16);
                }
                o[(size_t)j * NBIN + j1] = rB;
            }
        }
    }
}

// ---------- Fallback (NCHW direct, correctness-only path) ----------
__global__ __launch_bounds__(256) void ROIPool_nchw_kernel(
    const float* __restrict__ inputs, const float* __restrict__ rois,
    const float* __restrict__ masks, float* __restrict__ out)
{
    const int k  = blockIdx.x;
    const int ph = blockIdx.y;
    const int c  = threadIdx.x;

    const float* roi = rois + k * 5;
    const int b  = (int)roi[0];
    const int sw = (int)rintf(roi[1] * SCALE);
    const int sh = (int)rintf(roi[2] * SCALE);
    const int ew = (int)rintf(roi[3] * SCALE);
    const int eh = (int)rintf(roi[4] * SCALE);
    const int roi_w = max(ew - sw + 1, 1);
    const int roi_h = max(eh - sh + 1, 1);

    const int hs = min(max((ph * roi_h) / P + sh, 0), HH);
    const int he = min(max(((ph + 1) * roi_h + P - 1) / P + sh, 0), HH);

    int wsb[P], web[P];
#pragma unroll
    for (int pw = 0; pw < P; ++pw) {
        wsb[pw] = min(max((pw * roi_w) / P + sw, 0), WW);
        web[pw] = min(max(((pw + 1) * roi_w + P - 1) / P + sw, 0), WW);
    }

    const float* f = inputs + ((size_t)b * CC + c) * (HH * WW);
    const float* m = masks  + (size_t)k * (HH * WW);

    float vmax[P];
#pragma unroll
    for (int pw = 0; pw < P; ++pw) vmax[pw] = -INFINITY;

    for (int h = hs; h < he; ++h) {
        const float* frow = f + h * WW;
        const float* mrow = m + h * WW;
#pragma unroll
        for (int pw = 0; pw < P; ++pw) {
            float v = vmax[pw];
            for (int w = wsb[pw]; w < web[pw]; ++w)
                if (mrow[w] > 0.5f) v = fmaxf(v, frow[w]);
            vmax[pw] = v;
        }
    }

    float* o = out + (((size_t)k * CC + c) * P + ph) * P;
#pragma unroll
    for (int pw = 0; pw < P; ++pw) {
        const float v = vmax[pw];
        o[pw] = isinf(v) ? 0.0f : v;
    }
}

extern "C" void kernel_launch(void* const* d_in, const int* in_sizes, int n_in,
                              void* d_out, int out_size, void* d_ws, size_t ws_size,
                              hipStream_t stream) {
    const float* inputs = (const float*)d_in[0];
    const float* rois   = (const float*)d_in[1];
    const float* masks  = (const float*)d_in[2];
    float* out = (float*)d_out;

    const size_t keys_bytes  = (size_t)BB * CC * HH * WW * sizeof(unsigned short); // 32 MiB
    const size_t mbits_bytes = (size_t)KK * HH * 2 * sizeof(unsigned long long);   // 1 MiB
    const size_t kb_bytes    = (size_t)KK * sizeof(unsigned int);                  // 2 KiB
    const size_t rb_bytes    = (size_t)KK * 8 * sizeof(unsigned short);            // 8 KiB
    const size_t cb_bytes    = (size_t)KK * 8 * sizeof(unsigned short);            // 8 KiB

    if (ws_size >= keys_bytes + mbits_bytes + kb_bytes + rb_bytes + cb_bytes) {
        char* p = (char*)d_ws;
        unsigned short* fT = (unsigned short*)p;              p += keys_bytes;
        unsigned long long* mb = (unsigned long long*)p;      p += mbits_bytes;
        unsigned int* kb = (unsigned int*)p;                  p += kb_bytes;
        unsigned short* rowb = (unsigned short*)p;            p += rb_bytes;
        unsigned short* colb = (unsigned short*)p;
        {
            dim3 grid(TRANS_BLOCKS + MASK_BLOCKS);
            dim3 block(1024);
            prep_fused<<<grid, block, 0, stream>>>(inputs, masks, rois, fT, mb,
                                                   kb, rowb, colb);
        }
        {
            dim3 grid(KK * 7);
            dim3 block(256);
            pool_pair<<<grid, block, 0, stream>>>((const unsigned int*)fT, kb,
                                                  rowb, colb, mb, out);
        }
    } else {
        dim3 grid(KK, P);
        dim3 block(CC);
        ROIPool_nchw_kernel<<<grid, block, 0, stream>>>(inputs, rois, masks, out);
    }
}

// Round 15
// 107.342 us; speedup vs baseline: 1.5122x; 1.2004x over previous
//
#include <hip/hip_runtime.h>
#include <math.h>

#define P 7
#define SCALE 0.125f
#define BB 4
#define CC 256
#define HH 128
#define WW 128
#define KK 512
#define NBIN 49
#define GPB 13            // bin-groups per ROI (4 bins each, 13*4 >= 49)
#define NXCD 8
#define RPX  (KK / NXCD)  // 64 ROIs per XCD slice

#define TRANS_BLOCKS 4096   // (HH*WW/64) * (CC/64) * BB
#define MASK_BLOCKS  4096   // KK*HH rows / 16 waves per block

__device__ __forceinline__ unsigned short f32_to_bf16_rne(float f) {
    unsigned int u = __float_as_uint(f);
    u += 0x7FFFu + ((u >> 16) & 1u);
    return (unsigned short)(u >> 16);
}

// Order-preserving bf16 -> u16 key. key 0 reserved = "empty/masked".
__device__ __forceinline__ unsigned short bf16_key(unsigned short b) {
    return (b & 0x8000u) ? (unsigned short)(~b) : (unsigned short)(b | 0x8000u);
}

__device__ __forceinline__ unsigned int pkmax_u16(unsigned int a, unsigned int b) {
    unsigned int d;
    asm("v_pk_max_u16 %0, %1, %2" : "=v"(d) : "v"(a), "v"(b));
    return d;
}

// ---- Fused prep: transpose+convert, mask->bitmask; block 0 sorts + geo ----
__global__ __launch_bounds__(1024) void prep_fused(
    const float* __restrict__ in, const float* __restrict__ masks,
    const float* __restrict__ rois,
    unsigned short* __restrict__ out, unsigned long long* __restrict__ mbits,
    unsigned int* __restrict__ kb, unsigned short* __restrict__ rowb,
    unsigned short* __restrict__ colb)
{
    __shared__ float tile[64][65];    // tile[channel][pixel]
    __shared__ int skey[KK];          // block 0 only (sort)
    const int bid = blockIdx.x;
    const int tid = threadIdx.x;

    if (bid < TRANS_BLOCKS) {
        const int p0 = (bid & 255) * 64;        // pixel tile
        const int c0 = ((bid >> 8) & 3) * 64;   // channel tile
        const int b  = bid >> 10;               // batch
        const int tx = tid & 63;
        const int ty = tid >> 6;                // 0..15

        const float* src = in + (size_t)b * CC * (HH * WW);
#pragma unroll
        for (int j = 0; j < 64; j += 16)
            tile[ty + j][tx] =
                __builtin_nontemporal_load(&src[(size_t)(c0 + ty + j) * (HH * WW) + p0 + tx]);
        __syncthreads();

        unsigned int* dst = (unsigned int*)(out + (size_t)b * (HH * WW) * CC);
#pragma unroll
        for (int i = 0; i < 2; ++i) {
            const int flat = i * 1024 + tid;
            const int px = flat >> 5;
            const int cp = flat & 31;
            const unsigned int lo = bf16_key(f32_to_bf16_rne(tile[cp * 2][px]));
            const unsigned int hi = bf16_key(f32_to_bf16_rne(tile[cp * 2 + 1][px]));
            dst[((size_t)(p0 + px) * CC + c0) / 2 + cp] = lo | (hi << 16);
        }

        if (bid == 0) {
            // sort 512 ROIs by (batch, start-row) + emit geometry records;
            // block 0 runs first so this hides under the other ~8K blocks
            __syncthreads();
            if (tid < KK) {
                const float* r = rois + (size_t)tid * 5;
                const int rb = (int)r[0];
                int rsh = (int)rintf(r[2] * SCALE);
                rsh = min(max(rsh, 0), HH - 1);
                skey[tid] = rb * HH + rsh;
            }
            __syncthreads();
            if (tid < KK) {
                const int mykey = skey[tid];
                int pos = 0;
                for (int j = 0; j < KK; ++j) {
                    const int kj = skey[j];
                    pos += (kj < mykey) || (kj == mykey && j < tid);
                }
                const float* r = rois + (size_t)tid * 5;
                const int b  = (int)r[0];
                const int sw = (int)rintf(r[1] * SCALE);
                const int sh = (int)rintf(r[2] * SCALE);
                const int ew = (int)rintf(r[3] * SCALE);
                const int eh = (int)rintf(r[4] * SCALE);
                const int roi_w = max(ew - sw + 1, 1);
                const int roi_h = max(eh - sh + 1, 1);
                kb[pos] = (unsigned int)tid | ((unsigned int)b << 16);
#pragma unroll
                for (int j = 0; j < P; ++j) {
                    const int hs = min(max((j * roi_h) / P + sh, 0), HH);
                    const int he = min(max(((j + 1) * roi_h + P - 1) / P + sh, 0), HH);
                    const int ws = min(max((j * roi_w) / P + sw, 0), WW);
                    const int we = min(max(((j + 1) * roi_w + P - 1) / P + sw, 0), WW);
                    rowb[(pos << 3) + j] = (unsigned short)(hs | (he << 8));
                    colb[(pos << 3) + j] = (unsigned short)(ws | (we << 8));
                }
            }
        }
    } else {
        const int mbid = bid - TRANS_BLOCKS;
        const int wv   = tid >> 6;              // 0..15
        const int lane = tid & 63;
        const int row  = mbid * 16 + wv;        // 0 .. KK*HH-1
        const float* mr = masks + (size_t)row * WW;
        const unsigned long long b0 = __ballot(mr[lane] > 0.5f);
        const unsigned long long b1 = __ballot(mr[64 + lane] > 0.5f);
        if (lane == 0) {
            mbits[(size_t)row * 2]     = b0;
            mbits[(size_t)row * 2 + 1] = b1;
        }
    }
}

// ---- Pool: one wave per bin (R10 structure) + geo-record prologue ----
__global__ __launch_bounds__(256) void pool_key(
    const unsigned int* __restrict__ fbase,         // [B,HW,C/2] packed keys
    const unsigned int* __restrict__ kb,            // [K] k | b<<16 (sorted)
    const unsigned short* __restrict__ rowb,        // [K,8] hs|he<<8 (sorted)
    const unsigned short* __restrict__ colb,        // [K,8] ws|we<<8 (sorted)
    const unsigned long long* __restrict__ mbits,   // [K,H,2]
    float* __restrict__ out)                        // [K,C,P,P]
{
    // XCD x processes sorted-slice [x*64, x*64+64)
    const int pid = blockIdx.x;
    const int x   = pid & (NXCD - 1);
    const int t   = pid >> 3;
    const int g   = t % GPB;
    const int q   = t / GPB;                // 0..63
    const int i   = x * RPX + q;            // sorted ROI index

    const int wv   = threadIdx.x >> 6;
    const int lane = threadIdx.x & 63;
    const int bi   = g * 4 + wv;
    if (bi >= NBIN) return;                 // wave-uniform
    const int ph = bi / P;
    const int pw = bi % P;

    const int half = lane >> 5;             // even/odd pixel of each pair
    const int c4   = (lane & 31) * 4;       // uint offset: 8 channels

    // prologue: independent small loads of precomputed records (L2-hot)
    const unsigned int kbv = kb[i];
    const int k = kbv & 0xFFFF;
    const int b = (kbv >> 16) & 0xFF;
    const unsigned int rb = rowb[(i << 3) + ph];
    const unsigned int cb = colb[(i << 3) + pw];
    const int hs = rb & 0xFF, he = (rb >> 8) & 0xFF;
    const int wl = cb & 0xFF, wr = (cb >> 8) & 0xFF;

    const unsigned int boff = (unsigned int)b * (HH * WW * (CC / 2));
    const unsigned long long* mrow = mbits + (size_t)k * (HH * 2);

    unsigned int a0 = 0, a1 = 0, a2 = 0, a3 = 0;   // packed key accumulators

#pragma unroll 4
    for (int h = hs; h < he; ++h) {
        const unsigned long long lo = mrow[2 * h];
        const unsigned long long hi = mrow[2 * h + 1];
        const unsigned int rowoff = boff + (unsigned int)h * (WW * (CC / 2));
        for (int w0 = wl; w0 < wr; w0 += 8) {
            // wave-uniform 8-bit mask chunk for pixels w0..w0+7
            unsigned long long v;
            if (w0 >= 64)      v = hi >> (w0 - 64);
            else if (w0 == 0)  v = lo;
            else               v = (lo >> w0) | (hi << (64 - w0));
            unsigned int chunk = (unsigned int)v & 0xFFu;
            const int n = wr - w0;                     // valid pixel count
            chunk &= (n >= 8) ? 0xFFu : ((1u << n) - 1u);

            uint4 kv[4];
#pragma unroll
            for (int p = 0; p < 4; ++p) {
                // clamp to wr-1: tail loads alias the last valid pixel (L1 hit)
                const unsigned int wc = (unsigned int)min(w0 + p * 2 + half, wr - 1);
                kv[p] = *(const uint4*)(fbase + rowoff + wc * (CC / 2) + c4);
            }
#pragma unroll
            for (int p = 0; p < 4; ++p) {
                const unsigned int sel = (chunk >> (p * 2 + half)) & 1u;
                const unsigned int msk = 0u - sel;     // 0 or ~0
                a0 = pkmax_u16(a0, kv[p].x & msk);
                a1 = pkmax_u16(a1, kv[p].y & msk);
                a2 = pkmax_u16(a2, kv[p].z & msk);
                a3 = pkmax_u16(a3, kv[p].w & msk);
            }
        }
    }

    // combine pixel-halves (lane i <-> i+32 hold same channels)
    a0 = pkmax_u16(a0, (unsigned int)__shfl_xor((int)a0, 32, 64));
    a1 = pkmax_u16(a1, (unsigned int)__shfl_xor((int)a1, 32, 64));
    a2 = pkmax_u16(a2, (unsigned int)__shfl_xor((int)a2, 32, 64));
    a3 = pkmax_u16(a3, (unsigned int)__shfl_xor((int)a3, 32, 64));

    if (half == 0) {
        const unsigned int acc[4] = {a0, a1, a2, a3};
        float* o = out + ((size_t)k * CC + (size_t)c4 * 2) * NBIN + ph * P + pw;
#pragma unroll
        for (int j = 0; j < 8; ++j) {
            const unsigned int d = acc[j >> 1];
            const unsigned int key = (j & 1) ? (d >> 16) : (d & 0xFFFFu);
            float r;
            if (key == 0u) {
                r = 0.0f;                       // empty / fully-masked bin
            } else {
                const unsigned int bbits =
                    (key & 0x8000u) ? (key ^ 0x8000u) : (~key & 0xFFFFu);
                r = __uint_as_float(bbits << 16);
            }
            o[(size_t)j * NBIN] = r;
        }
    }
}

// ---------- Fallback (NCHW direct, correctness-only path) ----------
__global__ __launch_bounds__(256) void ROIPool_nchw_kernel(
    const float* __restrict__ inputs, const float* __restrict__ rois,
    const float* __restrict__ masks, float* __restrict__ out)
{
    const int k  = blockIdx.x;
    const int ph = blockIdx.y;
    const int c  = threadIdx.x;

    const float* roi = rois + k * 5;
    const int b  = (int)roi[0];
    const int sw = (int)rintf(roi[1] * SCALE);
    const int sh = (int)rintf(roi[2] * SCALE);
    const int ew = (int)rintf(roi[3] * SCALE);
    const int eh = (int)rintf(roi[4] * SCALE);
    const int roi_w = max(ew - sw + 1, 1);
    const int roi_h = max(eh - sh + 1, 1);

    const int hs = min(max((ph * roi_h) / P + sh, 0), HH);
    const int he = min(max(((ph + 1) * roi_h + P - 1) / P + sh, 0), HH);

    int wsb[P], web[P];
#pragma unroll
    for (int pw = 0; pw < P; ++pw) {
        wsb[pw] = min(max((pw * roi_w) / P + sw, 0), WW);
        web[pw] = min(max(((pw + 1) * roi_w + P - 1) / P + sw, 0), WW);
    }

    const float* f = inputs + ((size_t)b * CC + c) * (HH * WW);
    const float* m = masks  + (size_t)k * (HH * WW);

    float vmax[P];
#pragma unroll
    for (int pw = 0; pw < P; ++pw) vmax[pw] = -INFINITY;

    for (int h = hs; h < he; ++h) {
        const float* frow = f + h * WW;
        const float* mrow = m + h * WW;
#pragma unroll
        for (int pw = 0; pw < P; ++pw) {
            float v = vmax[pw];
            for (int w = wsb[pw]; w < web[pw]; ++w)
                if (mrow[w] > 0.5f) v = fmaxf(v, frow[w]);
            vmax[pw] = v;
        }
    }

    float* o = out + (((size_t)k * CC + c) * P + ph) * P;
#pragma unroll
    for (int pw = 0; pw < P; ++pw) {
        const float v = vmax[pw];
        o[pw] = isinf(v) ? 0.0f : v;
    }
}

extern "C" void kernel_launch(void* const* d_in, const int* in_sizes, int n_in,
                              void* d_out, int out_size, void* d_ws, size_t ws_size,
                              hipStream_t stream) {
    const float* inputs = (const float*)d_in[0];
    const float* rois   = (const float*)d_in[1];
    const float* masks  = (const float*)d_in[2];
    float* out = (float*)d_out;

    const size_t keys_bytes  = (size_t)BB * CC * HH * WW * sizeof(unsigned short); // 32 MiB
    const size_t mbits_bytes = (size_t)KK * HH * 2 * sizeof(unsigned long long);   // 1 MiB
    const size_t kb_bytes    = (size_t)KK * sizeof(unsigned int);                  // 2 KiB
    const size_t rb_bytes    = (size_t)KK * 8 * sizeof(unsigned short);            // 8 KiB
    const size_t cb_bytes    = (size_t)KK * 8 * sizeof(unsigned short);            // 8 KiB

    if (ws_size >= keys_bytes + mbits_bytes + kb_bytes + rb_bytes + cb_bytes) {
        char* p = (char*)d_ws;
        unsigned short* fT = (unsigned short*)p;              p += keys_bytes;
        unsigned long long* mb = (unsigned long long*)p;      p += mbits_bytes;
        unsigned int* kb = (unsigned int*)p;                  p += kb_bytes;
        unsigned short* rowb = (unsigned short*)p;            p += rb_bytes;
        unsigned short* colb = (unsigned short*)p;
        {
            dim3 grid(TRANS_BLOCKS + MASK_BLOCKS);
            dim3 block(1024);
            prep_fused<<<grid, block, 0, stream>>>(inputs, masks, rois, fT, mb,
                                                   kb, rowb, colb);
        }
        {
            dim3 grid(KK * GPB);
            dim3 block(256);
            pool_key<<<grid, block, 0, stream>>>((const unsigned int*)fT, kb,
                                                 rowb, colb, mb, out);
        }
    } else {
        dim3 grid(KK, P);
        dim3 block(CC);
        ROIPool_nchw_kernel<<<grid, block, 0, stream>>>(inputs, rois, masks, out);
    }
}

// Round 16
// 105.358 us; speedup vs baseline: 1.5406x; 1.0188x over previous
//
#include <hip/hip_runtime.h>
#include <math.h>

#define P 7
#define SCALE 0.125f
#define BB 4
#define CC 256
#define HH 128
#define WW 128
#define KK 512
#define NBIN 49
#define GPB 13            // bin-groups per ROI (4 bins each, 13*4 >= 49)
#define NXCD 8
#define RPX  (KK / NXCD)  // 64 ROIs per XCD slice

#define TRANS_BLOCKS 4096   // (HH*WW/64) * (CC/64) * BB
#define MASK_BLOCKS  4096   // KK*HH rows / 16 waves per block

__device__ __forceinline__ unsigned short f32_to_bf16_rne(float f) {
    unsigned int u = __float_as_uint(f);
    u += 0x7FFFu + ((u >> 16) & 1u);
    return (unsigned short)(u >> 16);
}

// Order-preserving bf16 -> u16 key. key 0 reserved = "empty/masked".
__device__ __forceinline__ unsigned short bf16_key(unsigned short b) {
    return (b & 0x8000u) ? (unsigned short)(~b) : (unsigned short)(b | 0x8000u);
}

__device__ __forceinline__ unsigned int pkmax_u16(unsigned int a, unsigned int b) {
    unsigned int d;
    asm("v_pk_max_u16 %0, %1, %2" : "=v"(d) : "v"(a), "v"(b));
    return d;
}

// ---- Fused prep: transpose+convert, mask->bitmask; block 0 sorts + geo ----
__global__ __launch_bounds__(1024) void prep_fused(
    const float* __restrict__ in, const float* __restrict__ masks,
    const float* __restrict__ rois,
    unsigned short* __restrict__ out, unsigned long long* __restrict__ mbits,
    unsigned int* __restrict__ kb, unsigned short* __restrict__ rowb,
    unsigned short* __restrict__ colb)
{
    __shared__ float tile[64][65];    // tile[channel][pixel]
    __shared__ int skey[KK];          // block 0 only (sort)
    const int bid = blockIdx.x;
    const int tid = threadIdx.x;

    if (bid < TRANS_BLOCKS) {
        const int p0 = (bid & 255) * 64;        // pixel tile
        const int c0 = ((bid >> 8) & 3) * 64;   // channel tile
        const int b  = bid >> 10;               // batch
        const int tx = tid & 63;
        const int ty = tid >> 6;                // 0..15

        const float* src = in + (size_t)b * CC * (HH * WW);
#pragma unroll
        for (int j = 0; j < 64; j += 16)
            tile[ty + j][tx] =
                __builtin_nontemporal_load(&src[(size_t)(c0 + ty + j) * (HH * WW) + p0 + tx]);
        __syncthreads();

        unsigned int* dst = (unsigned int*)(out + (size_t)b * (HH * WW) * CC);
#pragma unroll
        for (int i = 0; i < 2; ++i) {
            const int flat = i * 1024 + tid;
            const int px = flat >> 5;
            const int cp = flat & 31;
            const unsigned int lo = bf16_key(f32_to_bf16_rne(tile[cp * 2][px]));
            const unsigned int hi = bf16_key(f32_to_bf16_rne(tile[cp * 2 + 1][px]));
            dst[((size_t)(p0 + px) * CC + c0) / 2 + cp] = lo | (hi << 16);
        }

        if (bid == 0) {
            // sort 512 ROIs by (batch, start-row) + emit geometry records;
            // block 0 runs first so this hides under the other ~8K blocks
            __syncthreads();
            if (tid < KK) {
                const float* r = rois + (size_t)tid * 5;
                const int rb = (int)r[0];
                int rsh = (int)rintf(r[2] * SCALE);
                rsh = min(max(rsh, 0), HH - 1);
                skey[tid] = rb * HH + rsh;
            }
            __syncthreads();
            if (tid < KK) {
                const int mykey = skey[tid];
                int pos = 0;
                for (int j = 0; j < KK; ++j) {
                    const int kj = skey[j];
                    pos += (kj < mykey) || (kj == mykey && j < tid);
                }
                const float* r = rois + (size_t)tid * 5;
                const int b  = (int)r[0];
                const int sw = (int)rintf(r[1] * SCALE);
                const int sh = (int)rintf(r[2] * SCALE);
                const int ew = (int)rintf(r[3] * SCALE);
                const int eh = (int)rintf(r[4] * SCALE);
                const int roi_w = max(ew - sw + 1, 1);
                const int roi_h = max(eh - sh + 1, 1);
                kb[pos] = (unsigned int)tid | ((unsigned int)b << 16);
#pragma unroll
                for (int j = 0; j < P; ++j) {
                    const int hs = min(max((j * roi_h) / P + sh, 0), HH);
                    const int he = min(max(((j + 1) * roi_h + P - 1) / P + sh, 0), HH);
                    const int ws = min(max((j * roi_w) / P + sw, 0), WW);
                    const int we = min(max(((j + 1) * roi_w + P - 1) / P + sw, 0), WW);
                    rowb[(pos << 3) + j] = (unsigned short)(hs | (he << 8));
                    colb[(pos << 3) + j] = (unsigned short)(ws | (we << 8));
                }
            }
        }
    } else {
        const int mbid = bid - TRANS_BLOCKS;
        const int wv   = tid >> 6;              // 0..15
        const int lane = tid & 63;
        const int row  = mbid * 16 + wv;        // 0 .. KK*HH-1
        const float* mr = masks + (size_t)row * WW;
        const unsigned long long b0 = __ballot(mr[lane] > 0.5f);
        const unsigned long long b1 = __ballot(mr[64 + lane] > 0.5f);
        if (lane == 0) {
            mbits[(size_t)row * 2]     = b0;
            mbits[(size_t)row * 2 + 1] = b1;
        }
    }
}

// ---- Pool: one wave per bin; width-specialized loops (exact load count) ----
__global__ __launch_bounds__(256) void pool_key(
    const unsigned int* __restrict__ fbase,         // [B,HW,C/2] packed keys
    const unsigned int* __restrict__ kb,            // [K] k | b<<16 (sorted)
    const unsigned short* __restrict__ rowb,        // [K,8] hs|he<<8 (sorted)
    const unsigned short* __restrict__ colb,        // [K,8] ws|we<<8 (sorted)
    const unsigned long long* __restrict__ mbits,   // [K,H,2]
    float* __restrict__ out)                        // [K,C,P,P]
{
    // XCD x processes sorted-slice [x*64, x*64+64)
    const int pid = blockIdx.x;
    const int x   = pid & (NXCD - 1);
    const int t   = pid >> 3;
    const int g   = t % GPB;
    const int q   = t / GPB;                // 0..63
    const int i   = x * RPX + q;            // sorted ROI index

    const int wv   = threadIdx.x >> 6;
    const int lane = threadIdx.x & 63;
    const int bi   = g * 4 + wv;
    if (bi >= NBIN) return;                 // wave-uniform
    const int ph = bi / P;
    const int pw = bi % P;

    const int half = lane >> 5;             // even/odd pixel of each pair
    const int c4   = (lane & 31) * 4;       // uint offset: 8 channels

    // prologue: independent small loads of precomputed records (L2-hot)
    const unsigned int kbv = kb[i];
    const int k = kbv & 0xFFFF;
    const int b = (kbv >> 16) & 0xFF;
    const unsigned int rb = rowb[(i << 3) + ph];
    const unsigned int cb = colb[(i << 3) + pw];
    const int hs = rb & 0xFF, he = (rb >> 8) & 0xFF;
    const int wl = cb & 0xFF, wr = (cb >> 8) & 0xFF;

    const unsigned int boff = (unsigned int)b * (HH * WW * (CC / 2));
    const unsigned long long* mrow = mbits + (size_t)k * (HH * 2);

    unsigned int a0 = 0, a1 = 0, a2 = 0, a3 = 0;   // packed key accumulators

    const int bw = wr - wl;

    // one row-chunk: NP pair-loads (exactly ceil(bw/2)), masked pkmax
#define ROW_CHUNK(W0, BR, NP) do {                                             \
        unsigned long long v;                                                  \
        const int s = (W0);                                                    \
        if (s >= 64)      v = hi >> (s - 64);                                  \
        else if (s == 0)  v = lo;                                              \
        else              v = (lo >> s) | (hi << (64 - s));                    \
        unsigned int chunk = (unsigned int)v & 0xFFu;                          \
        const int n = (BR) - s;                                                \
        chunk &= (n >= 8) ? 0xFFu : ((1u << n) - 1u);                          \
        const unsigned int rowoff = boff + (unsigned int)h * (WW * (CC / 2));  \
        if (NP >= 1) {                                                         \
            const unsigned int wc = (unsigned int)min(s + 0 + half, (BR) - 1); \
            const uint4 kv = *(const uint4*)(fbase + rowoff + wc * (CC / 2) + c4); \
            const unsigned int m = 0u - ((chunk >> (0 + half)) & 1u);          \
            a0 = pkmax_u16(a0, kv.x & m); a1 = pkmax_u16(a1, kv.y & m);        \
            a2 = pkmax_u16(a2, kv.z & m); a3 = pkmax_u16(a3, kv.w & m);        \
        }                                                                      \
        if (NP >= 2) {                                                         \
            const unsigned int wc = (unsigned int)min(s + 2 + half, (BR) - 1); \
            const uint4 kv = *(const uint4*)(fbase + rowoff + wc * (CC / 2) + c4); \
            const unsigned int m = 0u - ((chunk >> (2 + half)) & 1u);          \
            a0 = pkmax_u16(a0, kv.x & m); a1 = pkmax_u16(a1, kv.y & m);        \
            a2 = pkmax_u16(a2, kv.z & m); a3 = pkmax_u16(a3, kv.w & m);        \
        }                                                                      \
        if (NP >= 3) {                                                         \
            const unsigned int wc = (unsigned int)min(s + 4 + half, (BR) - 1); \
            const uint4 kv = *(const uint4*)(fbase + rowoff + wc * (CC / 2) + c4); \
            const unsigned int m = 0u - ((chunk >> (4 + half)) & 1u);          \
            a0 = pkmax_u16(a0, kv.x & m); a1 = pkmax_u16(a1, kv.y & m);        \
            a2 = pkmax_u16(a2, kv.z & m); a3 = pkmax_u16(a3, kv.w & m);        \
        }                                                                      \
        if (NP >= 4) {                                                         \
            const unsigned int wc = (unsigned int)min(s + 6 + half, (BR) - 1); \
            const uint4 kv = *(const uint4*)(fbase + rowoff + wc * (CC / 2) + c4); \
            const unsigned int m = 0u - ((chunk >> (6 + half)) & 1u);          \
            a0 = pkmax_u16(a0, kv.x & m); a1 = pkmax_u16(a1, kv.y & m);        \
            a2 = pkmax_u16(a2, kv.z & m); a3 = pkmax_u16(a3, kv.w & m);        \
        }                                                                      \
    } while (0)

#define NARROW_LOOP(NP)                                                        \
    _Pragma("unroll 4")                                                        \
    for (int h = hs; h < he; ++h) {                                            \
        const unsigned long long lo = mrow[2 * h];                             \
        const unsigned long long hi = mrow[2 * h + 1];                         \
        ROW_CHUNK(wl, wr, NP);                                                 \
    }

    if (bw > 0 && he > hs) {
        if (bw <= 8) {
            // common case: exact load count, branch chosen once per wave
            const int npair = (bw + 1) >> 1;    // 1..4
            switch (npair) {
                case 1: NARROW_LOOP(1); break;
                case 2: NARROW_LOOP(2); break;
                case 3: NARROW_LOOP(3); break;
                default: NARROW_LOOP(4); break;
            }
        } else {
            // wide bins: generic multi-chunk path (full 4-load chunks)
#pragma unroll 2
            for (int h = hs; h < he; ++h) {
                const unsigned long long lo = mrow[2 * h];
                const unsigned long long hi = mrow[2 * h + 1];
                for (int w0 = wl; w0 < wr; w0 += 8) {
                    ROW_CHUNK(w0, wr, 4);
                }
            }
        }
    }
#undef NARROW_LOOP
#undef ROW_CHUNK

    // combine pixel-halves (lane i <-> i+32 hold same channels)
    a0 = pkmax_u16(a0, (unsigned int)__shfl_xor((int)a0, 32, 64));
    a1 = pkmax_u16(a1, (unsigned int)__shfl_xor((int)a1, 32, 64));
    a2 = pkmax_u16(a2, (unsigned int)__shfl_xor((int)a2, 32, 64));
    a3 = pkmax_u16(a3, (unsigned int)__shfl_xor((int)a3, 32, 64));

    if (half == 0) {
        const unsigned int acc[4] = {a0, a1, a2, a3};
        float* o = out + ((size_t)k * CC + (size_t)c4 * 2) * NBIN + ph * P + pw;
#pragma unroll
        for (int j = 0; j < 8; ++j) {
            const unsigned int d = acc[j >> 1];
            const unsigned int key = (j & 1) ? (d >> 16) : (d & 0xFFFFu);
            float r;
            if (key == 0u) {
                r = 0.0f;                       // empty / fully-masked bin
            } else {
                const unsigned int bbits =
                    (key & 0x8000u) ? (key ^ 0x8000u) : (~key & 0xFFFFu);
                r = __uint_as_float(bbits << 16);
            }
            o[(size_t)j * NBIN] = r;
        }
    }
}

// ---------- Fallback (NCHW direct, correctness-only path) ----------
__global__ __launch_bounds__(256) void ROIPool_nchw_kernel(
    const float* __restrict__ inputs, const float* __restrict__ rois,
    const float* __restrict__ masks, float* __restrict__ out)
{
    const int k  = blockIdx.x;
    const int ph = blockIdx.y;
    const int c  = threadIdx.x;

    const float* roi = rois + k * 5;
    const int b  = (int)roi[0];
    const int sw = (int)rintf(roi[1] * SCALE);
    const int sh = (int)rintf(roi[2] * SCALE);
    const int ew = (int)rintf(roi[3] * SCALE);
    const int eh = (int)rintf(roi[4] * SCALE);
    const int roi_w = max(ew - sw + 1, 1);
    const int roi_h = max(eh - sh + 1, 1);

    const int hs = min(max((ph * roi_h) / P + sh, 0), HH);
    const int he = min(max(((ph + 1) * roi_h + P - 1) / P + sh, 0), HH);

    int wsb[P], web[P];
#pragma unroll
    for (int pw = 0; pw < P; ++pw) {
        wsb[pw] = min(max((pw * roi_w) / P + sw, 0), WW);
        web[pw] = min(max(((pw + 1) * roi_w + P - 1) / P + sw, 0), WW);
    }

    const float* f = inputs + ((size_t)b * CC + c) * (HH * WW);
    const float* m = masks  + (size_t)k * (HH * WW);

    float vmax[P];
#pragma unroll
    for (int pw = 0; pw < P; ++pw) vmax[pw] = -INFINITY;

    for (int h = hs; h < he; ++h) {
        const float* frow = f + h * WW;
        const float* mrow = m + h * WW;
#pragma unroll
        for (int pw = 0; pw < P; ++pw) {
            float v = vmax[pw];
            for (int w = wsb[pw]; w < web[pw]; ++w)
                if (mrow[w] > 0.5f) v = fmaxf(v, frow[w]);
            vmax[pw] = v;
        }
    }

    float* o = out + (((size_t)k * CC + c) * P + ph) * P;
#pragma unroll
    for (int pw = 0; pw < P; ++pw) {
        const float v = vmax[pw];
        o[pw] = isinf(v) ? 0.0f : v;
    }
}

extern "C" void kernel_launch(void* const* d_in, const int* in_sizes, int n_in,
                              void* d_out, int out_size, void* d_ws, size_t ws_size,
                              hipStream_t stream) {
    const float* inputs = (const float*)d_in[0];
    const float* rois   = (const float*)d_in[1];
    const float* masks  = (const float*)d_in[2];
    float* out = (float*)d_out;

    const size_t keys_bytes  = (size_t)BB * CC * HH * WW * sizeof(unsigned short); // 32 MiB
    const size_t mbits_bytes = (size_t)KK * HH * 2 * sizeof(unsigned long long);   // 1 MiB
    const size_t kb_bytes    = (size_t)KK * sizeof(unsigned int);                  // 2 KiB
    const size_t rb_bytes    = (size_t)KK * 8 * sizeof(unsigned short);            // 8 KiB
    const size_t cb_bytes    = (size_t)KK * 8 * sizeof(unsigned short);            // 8 KiB

    if (ws_size >= keys_bytes + mbits_bytes + kb_bytes + rb_bytes + cb_bytes) {
        char* p = (char*)d_ws;
        unsigned short* fT = (unsigned short*)p;              p += keys_bytes;
        unsigned long long* mb = (unsigned long long*)p;      p += mbits_bytes;
        unsigned int* kb = (unsigned int*)p;                  p += kb_bytes;
        unsigned short* rowb = (unsigned short*)p;            p += rb_bytes;
        unsigned short* colb = (unsigned short*)p;
        {
            dim3 grid(TRANS_BLOCKS + MASK_BLOCKS);
            dim3 block(1024);
            prep_fused<<<grid, block, 0, stream>>>(inputs, masks, rois, fT, mb,
                                                   kb, rowb, colb);
        }
        {
            dim3 grid(KK * GPB);
            dim3 block(256);
            pool_key<<<grid, block, 0, stream>>>((const unsigned int*)fT, kb,
                                                 rowb, colb, mb, out);
        }
    } else {
        dim3 grid(KK, P);
        dim3 block(CC);
        ROIPool_nchw_kernel<<<grid, block, 0, stream>>>(inputs, rois, masks, out);
    }
}